// Round 3
// baseline (7366.885 us; speedup 1.0000x reference)
//
#include <hip/hip_runtime.h>
#include <hip/hip_bf16.h>

typedef __hip_bfloat16 bf16;
#define BF2F(x) __bfloat162float(x)

// dual-dtype input load: f32 ? float : bf16
__device__ __forceinline__ float ldin(const void* p, size_t i, int f32) {
  return f32 ? ((const float*)p)[i] : BF2F(((const bf16*)p)[i]);
}

// ---------------- dtype detection: flag[0] = 0 (bf16) or 1 (f32) ----------------
__global__ void detect_kernel(const void* x, int* flag) {
  if (threadIdx.x == 0) {
    const unsigned short* u = (const unsigned short*)x;
    int sane = 0;
    for (int i = 0; i < 128; ++i) {
      unsigned short h = u[i];
      int e = (h >> 7) & 0xFF;
      if ((e >= 117 && e <= 133) || (h & 0x7FFF) == 0) ++sane;
    }
    flag[0] = (sane >= 100) ? 0 : 1;
  }
}

// ---------------- NCHW(input dtype) -> NHWC(fp32) ----------------
__global__ void nchw2nhwc_kernel(const void* __restrict__ in, float* __restrict__ out,
                                 const int* __restrict__ flag, int B, int C, int HW) {
  int i = blockIdx.x * blockDim.x + threadIdx.x;
  int total = B * C * HW;
  if (i >= total) return;
  int f32 = flag[0];
  int c = i % C; int p = (i / C) % HW; int b = i / (C * HW);
  out[i] = ldin(in, ((size_t)b * C + c) * HW + p, f32);
}

// ---------------- weight transform: w[co][ci][k2] -> wt[co][k2*C+ci] (bf16) ----------------
__global__ void wt_kernel(const void* __restrict__ w, bf16* __restrict__ wt,
                          const int* __restrict__ flag, int N, int C) {
  int i = blockIdx.x * blockDim.x + threadIdx.x;
  if (i >= N * 9 * C) return;
  int f32 = flag[0];
  int ci = i % C; int k2 = (i / C) % 9; int co = i / (9 * C);
  wt[i] = __float2bfloat16(ldin(w, ((size_t)co * C + ci) * 9 + k2, f32));
}

// ---------------- deformable bilinear sampling (chunked): S[mLocal][k2][ci] ----------------
__global__ void deform_sample_kernel(const float* __restrict__ act, const void* __restrict__ off,
                                     const int* __restrict__ flag,
                                     float* __restrict__ S, int m0, int B, int H, int W, int C) {
  int f32 = flag[0];
  int m = m0 + blockIdx.x;
  int HW = H * W;
  int b = m / HW; int p = m - b * HW; int y = p / W; int x = p - y * W;
  size_t obase = (size_t)b * 18 * HW + p;
  for (int k2 = 0; k2 < 9; ++k2) {
    float dy = ldin(off, obase + (size_t)(2 * k2) * HW, f32);
    float dx = ldin(off, obase + (size_t)(2 * k2 + 1) * HW, f32);
    float py = (float)(y + k2 / 3 - 1) + dy;
    float px = (float)(x + k2 % 3 - 1) + dx;
    float y0f = floorf(py), x0f = floorf(px);
    float wy = py - y0f, wx = px - x0f;
    int iy0 = (int)y0f, ix0 = (int)x0f;
    int iy1 = iy0 + 1, ix1 = ix0 + 1;
    float w00 = (1.f - wy) * (1.f - wx), w01 = (1.f - wy) * wx;
    float w10 = wy * (1.f - wx), w11 = wy * wx;
    if (iy0 < 0 || iy0 >= H) { w00 = 0.f; w01 = 0.f; }
    if (iy1 < 0 || iy1 >= H) { w10 = 0.f; w11 = 0.f; }
    if (ix0 < 0 || ix0 >= W) { w00 = 0.f; w10 = 0.f; }
    if (ix1 < 0 || ix1 >= W) { w01 = 0.f; w11 = 0.f; }
    int cy0 = min(max(iy0, 0), H - 1), cy1 = min(max(iy1, 0), H - 1);
    int cx0 = min(max(ix0, 0), W - 1), cx1 = min(max(ix1, 0), W - 1);
    const float* p00 = act + ((size_t)b * HW + cy0 * W + cx0) * C;
    const float* p01 = act + ((size_t)b * HW + cy0 * W + cx1) * C;
    const float* p10 = act + ((size_t)b * HW + cy1 * W + cx0) * C;
    const float* p11 = act + ((size_t)b * HW + cy1 * W + cx1) * C;
    float* so = S + ((size_t)blockIdx.x * 9 + k2) * C;
    for (int c = threadIdx.x; c < C; c += blockDim.x) {
      so[c] = w00 * p00[c] + w01 * p01[c] + w10 * p10[c] + w11 * p11[c];
    }
  }
}

// ---------------- GEMM: C[M,N] = A[M,K](f32) * B[N,K]^T + bias, opt relu ----------------
#define BM 64
#define BN 64
#define BK 16

__global__ __launch_bounds__(256) void gemm_kernel(
    const float* __restrict__ A, const void* __restrict__ Bw, const int* __restrict__ bmode,
    const void* __restrict__ bias, const int* __restrict__ biasmode,
    float* __restrict__ Cf, void* __restrict__ Cfinal, const int* __restrict__ outmode,
    int M, int N, int K, int relu) {
  __shared__ float As[BK][BM + 4];
  __shared__ float Bs[BK][BN + 4];
  int bm = bmode[0];
  int sm = biasmode[0];
  int om = outmode[0];
  int tid = threadIdx.x;
  int tx = tid % 16, ty = tid / 16;
  int m0 = blockIdx.x * BM, n0 = blockIdx.y * BN;
  float acc[4][4] = {{0.f}};
  for (int k0 = 0; k0 < K; k0 += BK) {
    for (int i = tid; i < BM * BK; i += 256) {
      int r = i / BK, c = i % BK;
      int gm = m0 + r, gk = k0 + c;
      As[c][r] = (gm < M && gk < K) ? A[(size_t)gm * K + gk] : 0.f;
    }
    for (int i = tid; i < BN * BK; i += 256) {
      int r = i / BK, c = i % BK;
      int gn = n0 + r, gk = k0 + c;
      Bs[c][r] = (gn < N && gk < K) ? ldin(Bw, (size_t)gn * K + gk, bm) : 0.f;
    }
    __syncthreads();
#pragma unroll
    for (int kk = 0; kk < BK; ++kk) {
      float4 av = *(const float4*)(&As[kk][ty * 4]);
      float4 bv = *(const float4*)(&Bs[kk][tx * 4]);
      float a[4] = {av.x, av.y, av.z, av.w};
      float b[4] = {bv.x, bv.y, bv.z, bv.w};
#pragma unroll
      for (int i = 0; i < 4; ++i)
#pragma unroll
        for (int j = 0; j < 4; ++j)
          acc[i][j] += a[i] * b[j];
    }
    __syncthreads();
  }
  for (int i = 0; i < 4; ++i) {
    int m = m0 + ty * 4 + i;
    if (m >= M) continue;
    for (int j = 0; j < 4; ++j) {
      int n = n0 + tx * 4 + j;
      if (n >= N) continue;
      float v = acc[i][j];
      if (bias) v += ldin(bias, n, sm);
      if (relu && v < 0.f) v = 0.f;
      if (Cfinal) {
        if (om) ((float*)Cfinal)[(size_t)m * N + n] = v;
        else    ((bf16*)Cfinal)[(size_t)m * N + n] = __float2bfloat16(v);
      } else {
        Cf[(size_t)m * N + n] = v;
      }
    }
  }
}

// ---------------- BN batch stats: partial sums + atomics ----------------
__global__ __launch_bounds__(256) void bn_stats_kernel(const float* __restrict__ x,
                                                       float* __restrict__ st,
                                                       int M, int C, int rowsPerBlock) {
  __shared__ float sh[512];
  int t = threadIdx.x;
  int r0 = blockIdx.x * rowsPerBlock;
  int r1 = min(M, r0 + rowsPerBlock);
  if (C >= 256) {
    for (int c = t; c < C; c += 256) {
      float s = 0.f, ss = 0.f;
      for (int r = r0; r < r1; ++r) {
        float v = x[(size_t)r * C + c];
        s += v; ss += v * v;
      }
      atomicAdd(&st[c], s); atomicAdd(&st[512 + c], ss);
    }
  } else {
    int rpb = 256 / C;
    int c = t % C; int ro = t / C;
    float s = 0.f, ss = 0.f;
    for (int r = r0 + ro; r < r1; r += rpb) {
      float v = x[(size_t)r * C + c];
      s += v; ss += v * v;
    }
    sh[t] = s; sh[256 + t] = ss;
    __syncthreads();
    if (ro == 0) {
      for (int k = 1; k < rpb; ++k) { s += sh[k * C + c]; ss += sh[256 + k * C + c]; }
      atomicAdd(&st[c], s); atomicAdd(&st[512 + c], ss);
    }
  }
}

__global__ void bn_finalize_kernel(float* __restrict__ st, const void* __restrict__ g,
                                   const void* __restrict__ bb, const int* __restrict__ flag,
                                   int M, int C) {
  int c = threadIdx.x;
  if (c >= C) return;
  int f32 = flag[0];
  float mean = st[c] / (float)M;
  float var = st[512 + c] / (float)M - mean * mean;
  if (var < 0.f) var = 0.f;
  float inv = 1.0f / sqrtf(var + 1e-5f);
  float sc = ldin(g, c, f32) * inv;
  st[1024 + c] = sc;
  st[1536 + c] = ldin(bb, c, f32) - mean * sc;
}

__global__ void bn_apply_kernel(float* __restrict__ x, const float* __restrict__ scale,
                                const float* __restrict__ shift, int total, int C) {
  int i = blockIdx.x * blockDim.x + threadIdx.x;
  if (i >= total) return;
  int c = i % C;
  float v = x[i] * scale[c] + shift[c];
  x[i] = v > 0.f ? v : 0.f;
}

// ---------------- permutation-indexed 2x2 max pool (NHWC) ----------------
__global__ void pool_kernel(const float* __restrict__ in, float* __restrict__ out,
                            const int* __restrict__ perm, const int* __restrict__ nperm,
                            int B, int H, int C, int total) {
  int i = blockIdx.x * blockDim.x + threadIdx.x;
  if (i >= total) return;
  int oH = H / 2; int oHW = oH * oH; int HW = H * H;
  int c = i % C; int j = (i / C) % oHW; int b = i / (C * oHW);
  int q = min(max(nperm[j], 0), oHW - 1);
  int qy = q / oH, qx = q % oH;
  float m = -INFINITY;
#pragma unroll
  for (int dy = 0; dy < 2; ++dy)
#pragma unroll
    for (int dx = 0; dx < 2; ++dx) {
      int p = min(max(perm[(2 * qy + dy) * H + (2 * qx + dx)], 0), HW - 1);
      float v = in[((size_t)b * HW + p) * C + c];
      m = fmaxf(m, v);
    }
  out[((size_t)b * oHW + j) * C + c] = m;
}

extern "C" void kernel_launch(void* const* d_in, const int* in_sizes, int n_in,
                              void* d_out, int out_size, void* d_ws, size_t ws_size,
                              hipStream_t stream) {
  const int Ci[13]  = {3, 64, 64, 128, 128, 256, 256, 256, 512, 512, 512, 512, 512};
  const int CoA[13] = {64, 64, 128, 128, 256, 256, 256, 512, 512, 512, 512, 512, 512};
  const int Rr[13]  = {32, 32, 16, 16, 8, 8, 8, 4, 4, 4, 2, 2, 2};
  const int poolAfter[13] = {-1, 0, -1, 1, -1, -1, 2, -1, -1, 3, -1, -1, 4};
  const int B = 32;

  // ---------- workspace carve, strictly within ws_size ----------
  size_t cursor = 0;
  auto alloc = [&](size_t bytes) {
    void* p = (char*)d_ws + cursor;
    cursor += (bytes + 255) & ~(size_t)255;
    return p;
  };
  int*   flag  = (int*)  alloc(256);                   // flag[0]=dtype mode, flag[1]=0 const
  float* stats = (float*)alloc((size_t)13 * 2048 * 4);
  float* fcA   = (float*)alloc((size_t)32 * 4096 * 4);
  float* fcB   = (float*)alloc((size_t)32 * 4096 * 4);
  float* A0    = (float*)alloc((size_t)2097152 * 4);   // 32768*64 fp32
  float* A1    = (float*)alloc((size_t)2097152 * 4);
  bf16*  WT    = (bf16*) alloc((size_t)2359296 * 2);   // 512*4608 bf16
  size_t remainBytes = (ws_size > cursor) ? (ws_size - cursor) : 0;
  size_t sFloats = remainBytes / 4;
  if (sFloats > (size_t)8388608) sFloats = 8388608;    // cap S at 32 MB
  if (sFloats < (size_t)294912)  sFloats = 294912;     // floor: 64 rows x K=4608
  float* S = (float*)alloc(sFloats * 4);
  (void)in_sizes; (void)n_in; (void)out_size;

  // zero flag + stats (adjacent), then detect input dtype
  hipMemsetAsync(flag, 0, 256 + (size_t)13 * 2048 * 4, stream);
  detect_kernel<<<1, 64, 0, stream>>>(d_in[0], flag);

  // input NCHW -> NHWC fp32
  {
    int total = B * 3 * 1024;
    nchw2nhwc_kernel<<<(total + 255) / 256, 256, 0, stream>>>(d_in[0], A0, flag, B, 3, 1024);
  }

  const int* ZERO = flag + 1;  // always 0 (bf16 / ws-float mode)

  float* cur = A0;
  float* oth = A1;
  for (int l = 0; l < 13; ++l) {
    int C = Ci[l], N = CoA[l], H = Rr[l];
    int M = B * H * H, K = 9 * C;
    const void* offp = d_in[1 + l * 5 + 0];
    const void* wp   = d_in[1 + l * 5 + 1];
    const void* bp   = d_in[1 + l * 5 + 2];
    const void* gp   = d_in[1 + l * 5 + 3];
    const void* bbp  = d_in[1 + l * 5 + 4];

    wt_kernel<<<(N * K + 255) / 256, 256, 0, stream>>>(wp, WT, flag, N, C);

    int MC = (int)((sFloats / (size_t)K) & ~(size_t)63);
    if (MC < 64) MC = 64;
    if (MC > M) MC = M;
    int thr = C <= 64 ? 64 : (C <= 128 ? 128 : 256);
    for (int r0 = 0; r0 < M; r0 += MC) {
      int Mc = min(MC, M - r0);
      deform_sample_kernel<<<Mc, thr, 0, stream>>>(cur, offp, flag, S, r0, B, H, H, C);
      dim3 gg((Mc + BM - 1) / BM, (N + BN - 1) / BN);
      gemm_kernel<<<gg, 256, 0, stream>>>(S, WT, ZERO, bp, flag,
                                          oth + (size_t)r0 * N, nullptr, ZERO,
                                          Mc, N, K, 0);
    }

    float* st = stats + (size_t)l * 2048;
    int rowsPer = 64;
    bn_stats_kernel<<<(M + rowsPer - 1) / rowsPer, 256, 0, stream>>>(oth, st, M, N, rowsPer);
    bn_finalize_kernel<<<1, 512, 0, stream>>>(st, gp, bbp, flag, M, N);
    bn_apply_kernel<<<((size_t)M * N + 255) / 256, 256, 0, stream>>>(
        oth, st + 1024, st + 1536, M * N, N);

    if (poolAfter[l] >= 0) {
      int pi = poolAfter[l];
      const int* perm  = (const int*)d_in[66 + pi * 2];
      const int* nperm = (const int*)d_in[66 + pi * 2 + 1];
      int oH = H / 2;
      int total = B * oH * oH * N;
      pool_kernel<<<(total + 255) / 256, 256, 0, stream>>>(oth, cur, perm, nperm, B, H, N, total);
    } else {
      float* t = cur; cur = oth; oth = t;
    }
  }

  // FC head: cur = [32, 512] fp32
  const void* fw1 = d_in[76]; const void* fb1 = d_in[77];
  const void* fw2 = d_in[78]; const void* fb2 = d_in[79];
  const void* fw3 = d_in[80]; const void* fb3 = d_in[81];
  {
    dim3 g1(1, 4096 / BN);
    gemm_kernel<<<g1, 256, 0, stream>>>(cur, fw1, flag, fb1, flag, fcA, nullptr, ZERO,
                                        32, 4096, 512, 1);
    gemm_kernel<<<g1, 256, 0, stream>>>(fcA, fw2, flag, fb2, flag, fcB, nullptr, ZERO,
                                        32, 4096, 4096, 1);
    dim3 g3(1, (100 + BN - 1) / BN);
    gemm_kernel<<<g3, 256, 0, stream>>>(fcB, fw3, flag, fb3, flag, nullptr, d_out, flag,
                                        32, 100, 4096, 0);
  }
}

// Round 7
// 2750.831 us; speedup vs baseline: 2.6781x; 2.6781x over previous
//
#include <hip/hip_runtime.h>
#include <hip/hip_bf16.h>

typedef __hip_bfloat16 bf16;
typedef __attribute__((ext_vector_type(8))) short short8;
typedef __attribute__((ext_vector_type(4))) float f32x4;
#define BF2F(x) __bfloat162float(x)

__device__ __forceinline__ unsigned short f2bfbits(float v) {
  bf16 h = __float2bfloat16(v);
  return *(unsigned short*)&h;
}
__device__ __forceinline__ float bfbits2f(unsigned short u) {
  bf16 h; *(unsigned short*)&h = u;
  return BF2F(h);
}

// ---------------- NCHW(f32) -> NHWC(f32) ----------------
__global__ void nchw2nhwc_kernel(const float* __restrict__ in, float* __restrict__ out,
                                 int B, int C, int HW) {
  int i = blockIdx.x * blockDim.x + threadIdx.x;
  int total = B * C * HW;
  if (i >= total) return;
  int c = i % C; int p = (i / C) % HW; int b = i / (C * HW);
  out[i] = in[((size_t)b * C + c) * HW + p];
}

// ---------------- weight transform: w[co][ci][k2] -> wt[co][k2*C+ci] (f32) ----------------
__global__ void wt_kernel(const float* __restrict__ w, float* __restrict__ wt, int N, int C) {
  int i = blockIdx.x * blockDim.x + threadIdx.x;
  if (i >= N * 9 * C) return;
  int ci = i % C; int k2 = (i / C) % 9; int co = i / (9 * C);
  wt[i] = w[((size_t)co * C + ci) * 9 + k2];
}

// ---------------- deformable bilinear sampling (chunked): S[mLocal][k2][ci] fp32 ----------------
__global__ void deform_sample_kernel(const float* __restrict__ act, const float* __restrict__ off,
                                     float* __restrict__ S, int m0, int B, int H, int W, int C) {
  int m = m0 + blockIdx.x;
  int HW = H * W;
  int b = m / HW; int p = m - b * HW; int y = p / W; int x = p - y * W;
  size_t ob = (size_t)b * 18 * HW + p;
  for (int k2 = 0; k2 < 9; ++k2) {
    float dy = off[ob + (size_t)(2 * k2) * HW];
    float dx = off[ob + (size_t)(2 * k2 + 1) * HW];
    float py = (float)(y + k2 / 3 - 1) + dy;
    float px = (float)(x + k2 % 3 - 1) + dx;
    float y0f = floorf(py), x0f = floorf(px);
    float wy = py - y0f, wx = px - x0f;
    int iy0 = (int)y0f, ix0 = (int)x0f;
    int iy1 = iy0 + 1, ix1 = ix0 + 1;
    float w00 = (1.f - wy) * (1.f - wx), w01 = (1.f - wy) * wx;
    float w10 = wy * (1.f - wx), w11 = wy * wx;
    if (iy0 < 0 || iy0 >= H) { w00 = 0.f; w01 = 0.f; }
    if (iy1 < 0 || iy1 >= H) { w10 = 0.f; w11 = 0.f; }
    if (ix0 < 0 || ix0 >= W) { w00 = 0.f; w10 = 0.f; }
    if (ix1 < 0 || ix1 >= W) { w01 = 0.f; w11 = 0.f; }
    int cy0 = min(max(iy0, 0), H - 1), cy1 = min(max(iy1, 0), H - 1);
    int cx0 = min(max(ix0, 0), W - 1), cx1 = min(max(ix1, 0), W - 1);
    const float* p00 = act + ((size_t)b * HW + cy0 * W + cx0) * C;
    const float* p01 = act + ((size_t)b * HW + cy0 * W + cx1) * C;
    const float* p10 = act + ((size_t)b * HW + cy1 * W + cx0) * C;
    const float* p11 = act + ((size_t)b * HW + cy1 * W + cx1) * C;
    float* so = S + ((size_t)blockIdx.x * 9 + k2) * C;
    for (int c = threadIdx.x; c < C; c += blockDim.x) {
      so[c] = w00 * p00[c] + w01 * p01[c] + w10 * p10[c] + w11 * p11[c];
    }
  }
}

// ---------------- MFMA GEMM: C[M,N] = A[M,K](f32) * B[N,K](f32)^T + bias, opt relu ----------
// Both operands split in-kernel into hi/lo bf16; 3-product MFMA (AhBh+AhBl+AlBh)
// gives fp32-grade precision. LDA=40 u16 (80 B row): >=32-elem K-tile,
// 16B-aligned rows, non-pow2 stride for bank spread.
#define LDA 40

union VecU {
  unsigned short u[8];
  short8 s;
};

__global__ __launch_bounds__(256) void mfma_gemm(
    const float* __restrict__ A, const float* __restrict__ Bw,
    const float* __restrict__ bias, float* __restrict__ Cf,
    int M, int N, int K, int relu) {
  __shared__ __align__(16) unsigned short sAh[64 * LDA];
  __shared__ __align__(16) unsigned short sAl[64 * LDA];
  __shared__ __align__(16) unsigned short sBh[64 * LDA];
  __shared__ __align__(16) unsigned short sBl[64 * LDA];

  int tid = threadIdx.x;
  int wave = tid >> 6, lane = tid & 63;
  int quad = lane >> 4, l15 = lane & 15;
  int wr = wave >> 1, wc = wave & 1;
  int m0 = blockIdx.x * 64, n0 = blockIdx.y * 64;

  f32x4 acc[2][2];
#pragma unroll
  for (int t = 0; t < 2; ++t)
#pragma unroll
    for (int u = 0; u < 2; ++u)
      acc[t][u] = (f32x4){0.f, 0.f, 0.f, 0.f};

  int r = tid >> 2;           // staging row 0..63
  int kk = (tid & 3) << 3;    // staging k offset 0,8,16,24
  bool vecOK = ((K & 7) == 0);

  for (int k0 = 0; k0 < K; k0 += 32) {
    __syncthreads();
    int gk = k0 + kk;
    {  // A tile: f32 -> (hi,lo) bf16 split
      int gm = m0 + r;
      unsigned short* dh = &sAh[r * LDA + kk];
      unsigned short* dl = &sAl[r * LDA + kk];
      float vv[8];
      if (gm < M && vecOK && gk + 8 <= K) {
        const float4* ap = (const float4*)(A + (size_t)gm * K + gk);
        float4 f0 = ap[0], f1 = ap[1];
        vv[0] = f0.x; vv[1] = f0.y; vv[2] = f0.z; vv[3] = f0.w;
        vv[4] = f1.x; vv[5] = f1.y; vv[6] = f1.z; vv[7] = f1.w;
      } else {
#pragma unroll
        for (int j = 0; j < 8; ++j)
          vv[j] = (gm < M && gk + j < K) ? A[(size_t)gm * K + gk + j] : 0.f;
      }
      VecU uh, ul;
#pragma unroll
      for (int j = 0; j < 8; ++j) {
        unsigned short hb = f2bfbits(vv[j]);
        uh.u[j] = hb;
        ul.u[j] = f2bfbits(vv[j] - bfbits2f(hb));
      }
      *(short8*)dh = uh.s;
      *(short8*)dl = ul.s;
    }
    {  // B tile: f32 -> (hi,lo) bf16 split
      int gn = n0 + r;
      unsigned short* dh = &sBh[r * LDA + kk];
      unsigned short* dl = &sBl[r * LDA + kk];
      float vv[8];
      if (gn < N && vecOK && gk + 8 <= K) {
        const float4* bp = (const float4*)(Bw + (size_t)gn * K + gk);
        float4 f0 = bp[0], f1 = bp[1];
        vv[0] = f0.x; vv[1] = f0.y; vv[2] = f0.z; vv[3] = f0.w;
        vv[4] = f1.x; vv[5] = f1.y; vv[6] = f1.z; vv[7] = f1.w;
      } else {
#pragma unroll
        for (int j = 0; j < 8; ++j)
          vv[j] = (gn < N && gk + j < K) ? Bw[(size_t)gn * K + gk + j] : 0.f;
      }
      VecU uh, ul;
#pragma unroll
      for (int j = 0; j < 8; ++j) {
        unsigned short hb = f2bfbits(vv[j]);
        uh.u[j] = hb;
        ul.u[j] = f2bfbits(vv[j] - bfbits2f(hb));
      }
      *(short8*)dh = uh.s;
      *(short8*)dl = ul.s;
    }
    __syncthreads();
    short8 ah0 = *(const short8*)&sAh[(wr * 32 + 0 + l15) * LDA + quad * 8];
    short8 ah1 = *(const short8*)&sAh[(wr * 32 + 16 + l15) * LDA + quad * 8];
    short8 al0 = *(const short8*)&sAl[(wr * 32 + 0 + l15) * LDA + quad * 8];
    short8 al1 = *(const short8*)&sAl[(wr * 32 + 16 + l15) * LDA + quad * 8];
    short8 bh0 = *(const short8*)&sBh[(wc * 32 + 0 + l15) * LDA + quad * 8];
    short8 bh1 = *(const short8*)&sBh[(wc * 32 + 16 + l15) * LDA + quad * 8];
    short8 bl0 = *(const short8*)&sBl[(wc * 32 + 0 + l15) * LDA + quad * 8];
    short8 bl1 = *(const short8*)&sBl[(wc * 32 + 16 + l15) * LDA + quad * 8];
    // hi*hi
    acc[0][0] = __builtin_amdgcn_mfma_f32_16x16x32_bf16(ah0, bh0, acc[0][0], 0, 0, 0);
    acc[0][1] = __builtin_amdgcn_mfma_f32_16x16x32_bf16(ah0, bh1, acc[0][1], 0, 0, 0);
    acc[1][0] = __builtin_amdgcn_mfma_f32_16x16x32_bf16(ah1, bh0, acc[1][0], 0, 0, 0);
    acc[1][1] = __builtin_amdgcn_mfma_f32_16x16x32_bf16(ah1, bh1, acc[1][1], 0, 0, 0);
    // hi*lo
    acc[0][0] = __builtin_amdgcn_mfma_f32_16x16x32_bf16(ah0, bl0, acc[0][0], 0, 0, 0);
    acc[0][1] = __builtin_amdgcn_mfma_f32_16x16x32_bf16(ah0, bl1, acc[0][1], 0, 0, 0);
    acc[1][0] = __builtin_amdgcn_mfma_f32_16x16x32_bf16(ah1, bl0, acc[1][0], 0, 0, 0);
    acc[1][1] = __builtin_amdgcn_mfma_f32_16x16x32_bf16(ah1, bl1, acc[1][1], 0, 0, 0);
    // lo*hi
    acc[0][0] = __builtin_amdgcn_mfma_f32_16x16x32_bf16(al0, bh0, acc[0][0], 0, 0, 0);
    acc[0][1] = __builtin_amdgcn_mfma_f32_16x16x32_bf16(al0, bh1, acc[0][1], 0, 0, 0);
    acc[1][0] = __builtin_amdgcn_mfma_f32_16x16x32_bf16(al1, bh0, acc[1][0], 0, 0, 0);
    acc[1][1] = __builtin_amdgcn_mfma_f32_16x16x32_bf16(al1, bh1, acc[1][1], 0, 0, 0);
  }

  // epilogue: D[m = subtile + quad*4 + reg][n = subtile + l15]
#pragma unroll
  for (int t = 0; t < 2; ++t)
#pragma unroll
    for (int reg = 0; reg < 4; ++reg) {
      int m = m0 + wr * 32 + t * 16 + quad * 4 + reg;
      if (m >= M) continue;
#pragma unroll
      for (int u = 0; u < 2; ++u) {
        int n = n0 + wc * 32 + u * 16 + l15;
        if (n >= N) continue;
        float v = acc[t][u][reg];
        if (bias) v += bias[n];
        if (relu && v < 0.f) v = 0.f;
        Cf[(size_t)m * N + n] = v;
      }
    }
}

// ---------------- BN batch stats: partial sums + atomics ----------------
__global__ __launch_bounds__(256) void bn_stats_kernel(const float* __restrict__ x,
                                                       float* __restrict__ st,
                                                       int M, int C, int rowsPerBlock) {
  __shared__ float sh[512];
  int t = threadIdx.x;
  int r0 = blockIdx.x * rowsPerBlock;
  int r1 = min(M, r0 + rowsPerBlock);
  if (C >= 256) {
    for (int c = t; c < C; c += 256) {
      float s = 0.f, ss = 0.f;
      for (int r = r0; r < r1; ++r) {
        float v = x[(size_t)r * C + c];
        s += v; ss += v * v;
      }
      atomicAdd(&st[c], s); atomicAdd(&st[512 + c], ss);
    }
  } else {
    int rpb = 256 / C;
    int c = t % C; int ro = t / C;
    float s = 0.f, ss = 0.f;
    for (int r = r0 + ro; r < r1; r += rpb) {
      float v = x[(size_t)r * C + c];
      s += v; ss += v * v;
    }
    sh[t] = s; sh[256 + t] = ss;
    __syncthreads();
    if (ro == 0) {
      for (int k = 1; k < rpb; ++k) { s += sh[k * C + c]; ss += sh[256 + k * C + c]; }
      atomicAdd(&st[c], s); atomicAdd(&st[512 + c], ss);
    }
  }
}

__global__ void bn_finalize_kernel(float* __restrict__ st, const float* __restrict__ g,
                                   const float* __restrict__ bb, int M, int C) {
  int c = threadIdx.x;
  if (c >= C) return;
  float mean = st[c] / (float)M;
  float var = st[512 + c] / (float)M - mean * mean;
  if (var < 0.f) var = 0.f;
  float inv = 1.0f / sqrtf(var + 1e-5f);
  float sc = g[c] * inv;
  st[1024 + c] = sc;
  st[1536 + c] = bb[c] - mean * sc;
}

__global__ void bn_apply_kernel(float* __restrict__ x, const float* __restrict__ scale,
                                const float* __restrict__ shift, int total, int C) {
  int i = blockIdx.x * blockDim.x + threadIdx.x;
  if (i >= total) return;
  int c = i % C;
  float v = x[i] * scale[c] + shift[c];
  x[i] = v > 0.f ? v : 0.f;
}

// ---------------- permutation-indexed 2x2 max pool (NHWC) ----------------
__global__ void pool_kernel(const float* __restrict__ in, float* __restrict__ out,
                            const int* __restrict__ perm, const int* __restrict__ nperm,
                            int B, int H, int C, int total) {
  int i = blockIdx.x * blockDim.x + threadIdx.x;
  if (i >= total) return;
  int oH = H / 2; int oHW = oH * oH; int HW = H * H;
  int c = i % C; int j = (i / C) % oHW; int b = i / (C * oHW);
  int q = min(max(nperm[j], 0), oHW - 1);
  int qy = q / oH, qx = q % oH;
  float m = -INFINITY;
#pragma unroll
  for (int dy = 0; dy < 2; ++dy)
#pragma unroll
    for (int dx = 0; dx < 2; ++dx) {
      int p = min(max(perm[(2 * qy + dy) * H + (2 * qx + dx)], 0), HW - 1);
      float v = in[((size_t)b * HW + p) * C + c];
      m = fmaxf(m, v);
    }
  out[((size_t)b * oHW + j) * C + c] = m;
}

extern "C" void kernel_launch(void* const* d_in, const int* in_sizes, int n_in,
                              void* d_out, int out_size, void* d_ws, size_t ws_size,
                              hipStream_t stream) {
  const int Ci[13]  = {3, 64, 64, 128, 128, 256, 256, 256, 512, 512, 512, 512, 512};
  const int CoA[13] = {64, 64, 128, 128, 256, 256, 256, 512, 512, 512, 512, 512, 512};
  const int Rr[13]  = {32, 32, 16, 16, 8, 8, 8, 4, 4, 4, 2, 2, 2};
  const int poolAfter[13] = {-1, 0, -1, 1, -1, -1, 2, -1, -1, 3, -1, -1, 4};
  const int B = 32;

  // ---------- workspace carve, strictly within ws_size ----------
  size_t cursor = 0;
  auto alloc = [&](size_t bytes) {
    void* p = (char*)d_ws + cursor;
    cursor += (bytes + 255) & ~(size_t)255;
    return p;
  };
  float* stats = (float*)alloc((size_t)13 * 2048 * 4);
  float* fcA   = (float*)alloc((size_t)32 * 4096 * 4);
  float* fcB   = (float*)alloc((size_t)32 * 4096 * 4);
  float* A0    = (float*)alloc((size_t)2097152 * 4);   // 32768*64 fp32
  float* A1    = (float*)alloc((size_t)2097152 * 4);
  float* WTf   = (float*)alloc((size_t)2359296 * 4);   // 512*4608 f32
  size_t remainBytes = (ws_size > cursor) ? (ws_size - cursor) : 0;
  size_t sFloats = remainBytes / 4;
  if (sFloats > (size_t)8388608) sFloats = 8388608;    // cap S at 32 MB
  if (sFloats < (size_t)294912)  sFloats = 294912;     // floor: 64 rows x K=4608
  float* S = (float*)alloc(sFloats * 4);
  (void)in_sizes; (void)n_in; (void)out_size;

  hipMemsetAsync(stats, 0, (size_t)13 * 2048 * 4, stream);

  // input NCHW f32 -> NHWC f32
  {
    int total = B * 3 * 1024;
    nchw2nhwc_kernel<<<(total + 255) / 256, 256, 0, stream>>>(
        (const float*)d_in[0], A0, B, 3, 1024);
  }

  float* cur = A0;
  float* oth = A1;
  for (int l = 0; l < 13; ++l) {
    int C = Ci[l], N = CoA[l], H = Rr[l];
    int M = B * H * H, K = 9 * C;
    const float* offp = (const float*)d_in[1 + l * 5 + 0];
    const float* wp   = (const float*)d_in[1 + l * 5 + 1];
    const float* bp   = (const float*)d_in[1 + l * 5 + 2];
    const float* gp   = (const float*)d_in[1 + l * 5 + 3];
    const float* bbp  = (const float*)d_in[1 + l * 5 + 4];

    wt_kernel<<<(N * K + 255) / 256, 256, 0, stream>>>(wp, WTf, N, C);

    int MC = (int)((sFloats / (size_t)K) & ~(size_t)63);
    if (MC < 64) MC = 64;
    if (MC > M) MC = M;
    int thr = C <= 64 ? 64 : (C <= 128 ? 128 : 256);
    for (int r0 = 0; r0 < M; r0 += MC) {
      int Mc = min(MC, M - r0);
      deform_sample_kernel<<<Mc, thr, 0, stream>>>(cur, offp, S, r0, B, H, H, C);
      dim3 gg((Mc + 63) / 64, (N + 63) / 64);
      mfma_gemm<<<gg, 256, 0, stream>>>(S, WTf, bp, oth + (size_t)r0 * N, Mc, N, K, 0);
    }

    float* st = stats + (size_t)l * 2048;
    int rowsPer = 64;
    bn_stats_kernel<<<(M + rowsPer - 1) / rowsPer, 256, 0, stream>>>(oth, st, M, N, rowsPer);
    bn_finalize_kernel<<<1, 512, 0, stream>>>(st, gp, bbp, M, N);
    bn_apply_kernel<<<((size_t)M * N + 255) / 256, 256, 0, stream>>>(
        oth, st + 1024, st + 1536, M * N, N);

    if (poolAfter[l] >= 0) {
      int pi = poolAfter[l];
      const int* perm  = (const int*)d_in[66 + pi * 2];
      const int* nperm = (const int*)d_in[66 + pi * 2 + 1];
      int oH = H / 2;
      int total = B * oH * oH * N;
      pool_kernel<<<(total + 255) / 256, 256, 0, stream>>>(oth, cur, perm, nperm, B, H, N, total);
    } else {
      float* t = cur; cur = oth; oth = t;
    }
  }

  // FC head: cur = [32, 512] fp32
  const float* fw1 = (const float*)d_in[76]; const float* fb1 = (const float*)d_in[77];
  const float* fw2 = (const float*)d_in[78]; const float* fb2 = (const float*)d_in[79];
  const float* fw3 = (const float*)d_in[80]; const float* fb3 = (const float*)d_in[81];
  {
    dim3 g1(1, 4096 / 64);
    mfma_gemm<<<g1, 256, 0, stream>>>(cur, fw1, fb1, fcA, 32, 4096, 512, 1);
    mfma_gemm<<<g1, 256, 0, stream>>>(fcA, fw2, fb2, fcB, 32, 4096, 4096, 1);
    dim3 g3(1, 2);
    mfma_gemm<<<g3, 256, 0, stream>>>(fcB, fw3, fb3, (float*)d_out, 32, 100, 4096, 0);
  }
}

// Round 8
// 1580.275 us; speedup vs baseline: 4.6618x; 1.7407x over previous
//
#include <hip/hip_runtime.h>
#include <hip/hip_bf16.h>

typedef __hip_bfloat16 bf16;
typedef __attribute__((ext_vector_type(8))) short short8;
typedef __attribute__((ext_vector_type(4))) float f32x4;
#define BF2F(x) __bfloat162float(x)

__device__ __forceinline__ unsigned short f2bfbits(float v) {
  bf16 h = __float2bfloat16(v);
  return *(unsigned short*)&h;
}
__device__ __forceinline__ float bfbits2f(unsigned short u) {
  bf16 h; *(unsigned short*)&h = u;
  return BF2F(h);
}

// ---------------- NCHW(f32) -> NHWC(f32) ----------------
__global__ void nchw2nhwc_kernel(const float* __restrict__ in, float* __restrict__ out,
                                 int B, int C, int HW) {
  int i = blockIdx.x * blockDim.x + threadIdx.x;
  int total = B * C * HW;
  if (i >= total) return;
  int c = i % C; int p = (i / C) % HW; int b = i / (C * HW);
  out[i] = in[((size_t)b * C + c) * HW + p];
}

// ---------------- weight transform: w[co][ci][k2] -> wt[co][k2*C+ci] (f32) ----------------
__global__ void wt_kernel(const float* __restrict__ w, float* __restrict__ wt, int N, int C) {
  int i = blockIdx.x * blockDim.x + threadIdx.x;
  if (i >= N * 9 * C) return;
  int ci = i % C; int k2 = (i / C) % 9; int co = i / (9 * C);
  wt[i] = w[((size_t)co * C + ci) * 9 + k2];
}

// ------- deformable sampling, fused BN(scale/shift)+ReLU on gathered values -------
__global__ void deform_sample_kernel(const float* __restrict__ act,
                                     const float* __restrict__ stp, int bnmode,
                                     const float* __restrict__ off,
                                     float* __restrict__ S, int m0, int B, int H, int W, int C) {
  int m = m0 + blockIdx.x;
  int HW = H * W;
  int b = m / HW; int p = m - b * HW; int y = p / W; int x = p - y * W;
  size_t ob = (size_t)b * 18 * HW + p;
  for (int k2 = 0; k2 < 9; ++k2) {
    float dy = off[ob + (size_t)(2 * k2) * HW];
    float dx = off[ob + (size_t)(2 * k2 + 1) * HW];
    float py = (float)(y + k2 / 3 - 1) + dy;
    float px = (float)(x + k2 % 3 - 1) + dx;
    float y0f = floorf(py), x0f = floorf(px);
    float wy = py - y0f, wx = px - x0f;
    int iy0 = (int)y0f, ix0 = (int)x0f;
    int iy1 = iy0 + 1, ix1 = ix0 + 1;
    float w00 = (1.f - wy) * (1.f - wx), w01 = (1.f - wy) * wx;
    float w10 = wy * (1.f - wx), w11 = wy * wx;
    if (iy0 < 0 || iy0 >= H) { w00 = 0.f; w01 = 0.f; }
    if (iy1 < 0 || iy1 >= H) { w10 = 0.f; w11 = 0.f; }
    if (ix0 < 0 || ix0 >= W) { w00 = 0.f; w10 = 0.f; }
    if (ix1 < 0 || ix1 >= W) { w01 = 0.f; w11 = 0.f; }
    int cy0 = min(max(iy0, 0), H - 1), cy1 = min(max(iy1, 0), H - 1);
    int cx0 = min(max(ix0, 0), W - 1), cx1 = min(max(ix1, 0), W - 1);
    const float* p00 = act + ((size_t)b * HW + cy0 * W + cx0) * C;
    const float* p01 = act + ((size_t)b * HW + cy0 * W + cx1) * C;
    const float* p10 = act + ((size_t)b * HW + cy1 * W + cx0) * C;
    const float* p11 = act + ((size_t)b * HW + cy1 * W + cx1) * C;
    float* so = S + ((size_t)blockIdx.x * 9 + k2) * C;
    for (int c = threadIdx.x; c < C; c += blockDim.x) {
      float v00 = p00[c], v01 = p01[c], v10 = p10[c], v11 = p11[c];
      if (bnmode) {
        float sc = stp[c], sh = stp[512 + c];
        v00 = fmaxf(v00 * sc + sh, 0.f);
        v01 = fmaxf(v01 * sc + sh, 0.f);
        v10 = fmaxf(v10 * sc + sh, 0.f);
        v11 = fmaxf(v11 * sc + sh, 0.f);
      }
      so[c] = w00 * v00 + w01 * v01 + w10 * v10 + w11 * v11;
    }
  }
}

// ---------------- MFMA GEMM, split-K capable ----------------
// C[M,N] = A[M,K](f32) * B[N,K](f32)^T ; both split to hi/lo bf16 in-kernel,
// 3-product MFMA. gridDim.z>1 => each z handles kPerZ K-columns, atomicAdd
// into pre-zeroed Cf (bias/relu must be 0/null in that case).
#define LDA 40

union VecU {
  unsigned short u[8];
  short8 s;
};

__global__ __launch_bounds__(256) void mfma_gemm(
    const float* __restrict__ A, const float* __restrict__ Bw,
    const float* __restrict__ bias, float* __restrict__ Cf,
    int M, int N, int K, int relu, int kPerZ) {
  __shared__ __align__(16) unsigned short sAh[64 * LDA];
  __shared__ __align__(16) unsigned short sAl[64 * LDA];
  __shared__ __align__(16) unsigned short sBh[64 * LDA];
  __shared__ __align__(16) unsigned short sBl[64 * LDA];

  int tid = threadIdx.x;
  int wave = tid >> 6, lane = tid & 63;
  int quad = lane >> 4, l15 = lane & 15;
  int wr = wave >> 1, wc = wave & 1;
  int m0 = blockIdx.x * 64, n0 = blockIdx.y * 64;
  int kStart = blockIdx.z * kPerZ;
  int kEnd = min(K, kStart + kPerZ);

  f32x4 acc[2][2];
#pragma unroll
  for (int t = 0; t < 2; ++t)
#pragma unroll
    for (int u = 0; u < 2; ++u)
      acc[t][u] = (f32x4){0.f, 0.f, 0.f, 0.f};

  int r = tid >> 2;           // staging row 0..63
  int kk = (tid & 3) << 3;    // staging k offset 0,8,16,24
  bool vecOK = ((K & 7) == 0);

  for (int k0 = kStart; k0 < kEnd; k0 += 32) {
    __syncthreads();
    int gk = k0 + kk;
    {  // A tile: f32 -> (hi,lo) bf16 split
      int gm = m0 + r;
      unsigned short* dh = &sAh[r * LDA + kk];
      unsigned short* dl = &sAl[r * LDA + kk];
      float vv[8];
      if (gm < M && vecOK && gk + 8 <= K) {
        const float4* ap = (const float4*)(A + (size_t)gm * K + gk);
        float4 f0 = ap[0], f1 = ap[1];
        vv[0] = f0.x; vv[1] = f0.y; vv[2] = f0.z; vv[3] = f0.w;
        vv[4] = f1.x; vv[5] = f1.y; vv[6] = f1.z; vv[7] = f1.w;
      } else {
#pragma unroll
        for (int j = 0; j < 8; ++j)
          vv[j] = (gm < M && gk + j < K) ? A[(size_t)gm * K + gk + j] : 0.f;
      }
      VecU uh, ul;
#pragma unroll
      for (int j = 0; j < 8; ++j) {
        unsigned short hb = f2bfbits(vv[j]);
        uh.u[j] = hb;
        ul.u[j] = f2bfbits(vv[j] - bfbits2f(hb));
      }
      *(short8*)dh = uh.s;
      *(short8*)dl = ul.s;
    }
    {  // B tile: f32 -> (hi,lo) bf16 split
      int gn = n0 + r;
      unsigned short* dh = &sBh[r * LDA + kk];
      unsigned short* dl = &sBl[r * LDA + kk];
      float vv[8];
      if (gn < N && vecOK && gk + 8 <= K) {
        const float4* bp = (const float4*)(Bw + (size_t)gn * K + gk);
        float4 f0 = bp[0], f1 = bp[1];
        vv[0] = f0.x; vv[1] = f0.y; vv[2] = f0.z; vv[3] = f0.w;
        vv[4] = f1.x; vv[5] = f1.y; vv[6] = f1.z; vv[7] = f1.w;
      } else {
#pragma unroll
        for (int j = 0; j < 8; ++j)
          vv[j] = (gn < N && gk + j < K) ? Bw[(size_t)gn * K + gk + j] : 0.f;
      }
      VecU uh, ul;
#pragma unroll
      for (int j = 0; j < 8; ++j) {
        unsigned short hb = f2bfbits(vv[j]);
        uh.u[j] = hb;
        ul.u[j] = f2bfbits(vv[j] - bfbits2f(hb));
      }
      *(short8*)dh = uh.s;
      *(short8*)dl = ul.s;
    }
    __syncthreads();
    short8 ah0 = *(const short8*)&sAh[(wr * 32 + 0 + l15) * LDA + quad * 8];
    short8 ah1 = *(const short8*)&sAh[(wr * 32 + 16 + l15) * LDA + quad * 8];
    short8 al0 = *(const short8*)&sAl[(wr * 32 + 0 + l15) * LDA + quad * 8];
    short8 al1 = *(const short8*)&sAl[(wr * 32 + 16 + l15) * LDA + quad * 8];
    short8 bh0 = *(const short8*)&sBh[(wc * 32 + 0 + l15) * LDA + quad * 8];
    short8 bh1 = *(const short8*)&sBh[(wc * 32 + 16 + l15) * LDA + quad * 8];
    short8 bl0 = *(const short8*)&sBl[(wc * 32 + 0 + l15) * LDA + quad * 8];
    short8 bl1 = *(const short8*)&sBl[(wc * 32 + 16 + l15) * LDA + quad * 8];
    acc[0][0] = __builtin_amdgcn_mfma_f32_16x16x32_bf16(ah0, bh0, acc[0][0], 0, 0, 0);
    acc[0][1] = __builtin_amdgcn_mfma_f32_16x16x32_bf16(ah0, bh1, acc[0][1], 0, 0, 0);
    acc[1][0] = __builtin_amdgcn_mfma_f32_16x16x32_bf16(ah1, bh0, acc[1][0], 0, 0, 0);
    acc[1][1] = __builtin_amdgcn_mfma_f32_16x16x32_bf16(ah1, bh1, acc[1][1], 0, 0, 0);
    acc[0][0] = __builtin_amdgcn_mfma_f32_16x16x32_bf16(ah0, bl0, acc[0][0], 0, 0, 0);
    acc[0][1] = __builtin_amdgcn_mfma_f32_16x16x32_bf16(ah0, bl1, acc[0][1], 0, 0, 0);
    acc[1][0] = __builtin_amdgcn_mfma_f32_16x16x32_bf16(ah1, bl0, acc[1][0], 0, 0, 0);
    acc[1][1] = __builtin_amdgcn_mfma_f32_16x16x32_bf16(ah1, bl1, acc[1][1], 0, 0, 0);
    acc[0][0] = __builtin_amdgcn_mfma_f32_16x16x32_bf16(al0, bh0, acc[0][0], 0, 0, 0);
    acc[0][1] = __builtin_amdgcn_mfma_f32_16x16x32_bf16(al0, bh1, acc[0][1], 0, 0, 0);
    acc[1][0] = __builtin_amdgcn_mfma_f32_16x16x32_bf16(al1, bh0, acc[1][0], 0, 0, 0);
    acc[1][1] = __builtin_amdgcn_mfma_f32_16x16x32_bf16(al1, bh1, acc[1][1], 0, 0, 0);
  }

  bool atomicMode = (gridDim.z > 1);
#pragma unroll
  for (int t = 0; t < 2; ++t)
#pragma unroll
    for (int reg = 0; reg < 4; ++reg) {
      int m = m0 + wr * 32 + t * 16 + quad * 4 + reg;
      if (m >= M) continue;
#pragma unroll
      for (int u = 0; u < 2; ++u) {
        int n = n0 + wc * 32 + u * 16 + l15;
        if (n >= N) continue;
        float v = acc[t][u][reg];
        if (atomicMode) {
          atomicAdd(&Cf[(size_t)m * N + n], v);
        } else {
          if (bias) v += bias[n];
          if (relu && v < 0.f) v = 0.f;
          Cf[(size_t)m * N + n] = v;
        }
      }
    }
}

// ---------------- bias (+optional relu) pass for split-K outputs ----------------
__global__ void bias_act_kernel(float* __restrict__ x, const float* __restrict__ bias,
                                int total, int C, int relu) {
  int i = blockIdx.x * blockDim.x + threadIdx.x;
  if (i >= total) return;
  float v = x[i] + bias[i % C];
  if (relu && v < 0.f) v = 0.f;
  x[i] = v;
}

// ---------------- BN batch stats ----------------
__global__ __launch_bounds__(256) void bn_stats_kernel(const float* __restrict__ x,
                                                       float* __restrict__ st,
                                                       int M, int C, int rowsPerBlock) {
  __shared__ float sh[512];
  int t = threadIdx.x;
  int r0 = blockIdx.x * rowsPerBlock;
  int r1 = min(M, r0 + rowsPerBlock);
  if (C >= 256) {
    for (int c = t; c < C; c += 256) {
      float s = 0.f, ss = 0.f;
      for (int r = r0; r < r1; ++r) {
        float v = x[(size_t)r * C + c];
        s += v; ss += v * v;
      }
      atomicAdd(&st[c], s); atomicAdd(&st[512 + c], ss);
    }
  } else {
    int rpb = 256 / C;
    int c = t % C; int ro = t / C;
    float s = 0.f, ss = 0.f;
    for (int r = r0 + ro; r < r1; r += rpb) {
      float v = x[(size_t)r * C + c];
      s += v; ss += v * v;
    }
    sh[t] = s; sh[256 + t] = ss;
    __syncthreads();
    if (ro == 0) {
      for (int k = 1; k < rpb; ++k) { s += sh[k * C + c]; ss += sh[256 + k * C + c]; }
      atomicAdd(&st[c], s); atomicAdd(&st[512 + c], ss);
    }
  }
}

__global__ void bn_finalize_kernel(float* __restrict__ st, const float* __restrict__ g,
                                   const float* __restrict__ bb, int M, int C) {
  int c = threadIdx.x;
  if (c >= C) return;
  float mean = st[c] / (float)M;
  float var = st[512 + c] / (float)M - mean * mean;
  if (var < 0.f) var = 0.f;
  float inv = 1.0f / sqrtf(var + 1e-5f);
  float sc = g[c] * inv;
  st[1024 + c] = sc;
  st[1536 + c] = bb[c] - mean * sc;
}

// -------- permuted 2x2 max pool with fused BN+ReLU on inputs --------
__global__ void pool_kernel(const float* __restrict__ in, const float* __restrict__ stp,
                            float* __restrict__ out,
                            const int* __restrict__ perm, const int* __restrict__ nperm,
                            int B, int H, int C, int total) {
  int i = blockIdx.x * blockDim.x + threadIdx.x;
  if (i >= total) return;
  int oH = H / 2; int oHW = oH * oH; int HW = H * H;
  int c = i % C; int j = (i / C) % oHW; int b = i / (C * oHW);
  float sc = stp[c], sh = stp[512 + c];
  int q = min(max(nperm[j], 0), oHW - 1);
  int qy = q / oH, qx = q % oH;
  float m = 0.f;  // post-ReLU values are >= 0
#pragma unroll
  for (int dy = 0; dy < 2; ++dy)
#pragma unroll
    for (int dx = 0; dx < 2; ++dx) {
      int p = min(max(perm[(2 * qy + dy) * H + (2 * qx + dx)], 0), HW - 1);
      float v = in[((size_t)b * HW + p) * C + c];
      v = fmaxf(v * sc + sh, 0.f);
      m = fmaxf(m, v);
    }
  out[((size_t)b * oHW + j) * C + c] = m;
}

static inline void pick_split(int gx, int gy, int K, int& zs, int& kPerZ) {
  int gxy = gx * gy;
  zs = 1;
  if (gxy < 192) {
    zs = (256 + gxy - 1) / gxy;
    int maxz = K / 32; if (maxz < 1) maxz = 1;
    if (zs > maxz) zs = maxz;
  }
  kPerZ = (((K + zs - 1) / zs) + 31) & ~31;
}

extern "C" void kernel_launch(void* const* d_in, const int* in_sizes, int n_in,
                              void* d_out, int out_size, void* d_ws, size_t ws_size,
                              hipStream_t stream) {
  const int Ci[13]  = {3, 64, 64, 128, 128, 256, 256, 256, 512, 512, 512, 512, 512};
  const int CoA[13] = {64, 64, 128, 128, 256, 256, 256, 512, 512, 512, 512, 512, 512};
  const int Rr[13]  = {32, 32, 16, 16, 8, 8, 8, 4, 4, 4, 2, 2, 2};
  const int poolAfter[13] = {-1, 0, -1, 1, -1, -1, 2, -1, -1, 3, -1, -1, 4};
  const int B = 32;

  size_t cursor = 0;
  auto alloc = [&](size_t bytes) {
    void* p = (char*)d_ws + cursor;
    cursor += (bytes + 255) & ~(size_t)255;
    return p;
  };
  float* stats = (float*)alloc((size_t)13 * 2048 * 4);
  float* fcA   = (float*)alloc((size_t)32 * 4096 * 4);
  float* fcB   = (float*)alloc((size_t)32 * 4096 * 4);
  float* A0    = (float*)alloc((size_t)2097152 * 4);   // 32768*64 fp32
  float* A1    = (float*)alloc((size_t)2097152 * 4);
  float* WTf   = (float*)alloc((size_t)2359296 * 4);   // 512*4608 f32
  size_t remainBytes = (ws_size > cursor) ? (ws_size - cursor) : 0;
  size_t sFloats = remainBytes / 4;
  if (sFloats > (size_t)8388608) sFloats = 8388608;    // cap S at 32 MB
  if (sFloats < (size_t)294912)  sFloats = 294912;     // floor: 64 rows x K=4608
  float* S = (float*)alloc(sFloats * 4);
  (void)in_sizes; (void)n_in; (void)out_size;

  hipMemsetAsync(stats, 0, (size_t)13 * 2048 * 4, stream);

  {
    int total = B * 3 * 1024;
    nchw2nhwc_kernel<<<(total + 255) / 256, 256, 0, stream>>>(
        (const float*)d_in[0], A0, B, 3, 1024);
  }

  float* cur = A0;
  float* oth = A1;
  int needBN = 0;
  float* stp = nullptr;

  for (int l = 0; l < 13; ++l) {
    int C = Ci[l], N = CoA[l], H = Rr[l];
    int M = B * H * H, K = 9 * C;
    const float* offp = (const float*)d_in[1 + l * 5 + 0];
    const float* wp   = (const float*)d_in[1 + l * 5 + 1];
    const float* gp   = (const float*)d_in[1 + l * 5 + 3];
    const float* bbp  = (const float*)d_in[1 + l * 5 + 4];
    float* st = stats + (size_t)l * 2048;

    wt_kernel<<<(N * K + 255) / 256, 256, 0, stream>>>(wp, WTf, N, C);

    int MC = (int)((sFloats / (size_t)K) & ~(size_t)63);
    if (MC < 64) MC = 64;
    if (MC > M) MC = M;
    int thr = C <= 64 ? 64 : (C <= 128 ? 128 : 256);
    for (int r0 = 0; r0 < M; r0 += MC) {
      int Mc = min(MC, M - r0);
      deform_sample_kernel<<<Mc, thr, 0, stream>>>(cur, stp, needBN, offp, S, r0, B, H, H, C);
      int gx = (Mc + 63) / 64, gy = (N + 63) / 64;
      int zs, kPerZ;
      pick_split(gx, gy, K, zs, kPerZ);
      if (zs > 1)
        hipMemsetAsync(oth + (size_t)r0 * N, 0, (size_t)Mc * N * 4, stream);
      dim3 gg(gx, gy, zs);
      mfma_gemm<<<gg, 256, 0, stream>>>(S, WTf, nullptr, oth + (size_t)r0 * N,
                                        Mc, N, K, 0, kPerZ);
    }

    int rowsPer = 64;
    bn_stats_kernel<<<(M + rowsPer - 1) / rowsPer, 256, 0, stream>>>(oth, st, M, N, rowsPer);
    bn_finalize_kernel<<<1, 512, 0, stream>>>(st, gp, bbp, M, N);

    if (poolAfter[l] >= 0) {
      int pi = poolAfter[l];
      const int* perm  = (const int*)d_in[66 + pi * 2];
      const int* nperm = (const int*)d_in[66 + pi * 2 + 1];
      int oH = H / 2;
      int total = B * oH * oH * N;
      pool_kernel<<<(total + 255) / 256, 256, 0, stream>>>(oth, st + 1024, cur,
                                                           perm, nperm, B, H, N, total);
      needBN = 0; stp = nullptr;
    } else {
      float* t = cur; cur = oth; oth = t;
      needBN = 1; stp = st + 1024;
    }
  }

  // FC head: cur = [32, 512] fp32 activated
  const float* fw1 = (const float*)d_in[76]; const float* fb1 = (const float*)d_in[77];
  const float* fw2 = (const float*)d_in[78]; const float* fb2 = (const float*)d_in[79];
  const float* fw3 = (const float*)d_in[80]; const float* fb3 = (const float*)d_in[81];
  {
    int zs, kPerZ;
    // FC1: 32x4096x512
    hipMemsetAsync(fcA, 0, (size_t)32 * 4096 * 4, stream);
    pick_split(1, 64, 512, zs, kPerZ);
    mfma_gemm<<<dim3(1, 64, zs), 256, 0, stream>>>(cur, fw1, nullptr, fcA,
                                                   32, 4096, 512, 0, kPerZ);
    bias_act_kernel<<<(32 * 4096 + 255) / 256, 256, 0, stream>>>(fcA, fb1, 32 * 4096, 4096, 1);
    // FC2: 32x4096x4096
    hipMemsetAsync(fcB, 0, (size_t)32 * 4096 * 4, stream);
    pick_split(1, 64, 4096, zs, kPerZ);
    mfma_gemm<<<dim3(1, 64, zs), 256, 0, stream>>>(fcA, fw2, nullptr, fcB,
                                                   32, 4096, 4096, 0, kPerZ);
    bias_act_kernel<<<(32 * 4096 + 255) / 256, 256, 0, stream>>>(fcB, fb2, 32 * 4096, 4096, 1);
    // FC3: 32x100x4096
    hipMemsetAsync(d_out, 0, (size_t)3200 * 4, stream);
    pick_split(1, 2, 4096, zs, kPerZ);
    mfma_gemm<<<dim3(1, 2, zs), 256, 0, stream>>>(fcB, fw3, nullptr, (float*)d_out,
                                                  32, 100, 4096, 0, kPerZ);
    bias_act_kernel<<<(3200 + 255) / 256, 256, 0, stream>>>((float*)d_out, fb3, 3200, 100, 0);
  }
}

// Round 9
// 1340.952 us; speedup vs baseline: 5.4938x; 1.1785x over previous
//
#include <hip/hip_runtime.h>
#include <hip/hip_bf16.h>

typedef __hip_bfloat16 bf16;
typedef __attribute__((ext_vector_type(8))) short short8;
typedef __attribute__((ext_vector_type(4))) float f32x4;
#define BF2F(x) __bfloat162float(x)

__device__ __forceinline__ unsigned short f2bfbits(float v) {
  bf16 h = __float2bfloat16(v);
  return *(unsigned short*)&h;
}
__device__ __forceinline__ float bfbits2f(unsigned short u) {
  bf16 h; *(unsigned short*)&h = u;
  return BF2F(h);
}

// ---------------- NCHW(f32) -> NHWC(f32) ----------------
__global__ void nchw2nhwc_kernel(const float* __restrict__ in, float* __restrict__ out,
                                 int B, int C, int HW) {
  int i = blockIdx.x * blockDim.x + threadIdx.x;
  int total = B * C * HW;
  if (i >= total) return;
  int c = i % C; int p = (i / C) % HW; int b = i / (C * HW);
  out[i] = in[((size_t)b * C + c) * HW + p];
}

// ---------------- weight transform: w[co][ci][k2] -> wt[co][k2*C+ci] (f32) ----------------
__global__ void wt_kernel(const float* __restrict__ w, float* __restrict__ wt, int N, int C) {
  int i = blockIdx.x * blockDim.x + threadIdx.x;
  if (i >= N * 9 * C) return;
  int ci = i % C; int k2 = (i / C) % 9; int co = i / (9 * C);
  wt[i] = w[((size_t)co * C + ci) * 9 + k2];
}

// ------- flattened deformable sampling: thread = (pixel, k2, c4-chunk) -------
// fused BN(scale/shift)+ReLU on gathered values; float4 channel chunks (C%4==0)
__global__ __launch_bounds__(256) void deform_sample_v2(
    const float* __restrict__ act, const float* __restrict__ stp, int bnmode,
    const float* __restrict__ off, float* __restrict__ S,
    int m0, int Mc, int B, int H, int W, int C) {
  int i = blockIdx.x * blockDim.x + threadIdx.x;
  int c4n = C >> 2;
  int total = Mc * 9 * c4n;
  if (i >= total) return;
  int c4 = i % c4n;
  int t = i / c4n;
  int k2 = t % 9;
  int ml = t / 9;
  int m = m0 + ml;
  int HW = H * W;
  int b = m / HW; int p = m - b * HW; int y = p / W; int x = p - y * W;
  size_t ob = (size_t)b * 18 * HW + p;
  float dy = off[ob + (size_t)(2 * k2) * HW];
  float dx = off[ob + (size_t)(2 * k2 + 1) * HW];
  float py = (float)(y + k2 / 3 - 1) + dy;
  float px = (float)(x + k2 % 3 - 1) + dx;
  float y0f = floorf(py), x0f = floorf(px);
  float wy = py - y0f, wx = px - x0f;
  int iy0 = (int)y0f, ix0 = (int)x0f;
  int iy1 = iy0 + 1, ix1 = ix0 + 1;
  float w00 = (1.f - wy) * (1.f - wx), w01 = (1.f - wy) * wx;
  float w10 = wy * (1.f - wx), w11 = wy * wx;
  if (iy0 < 0 || iy0 >= H) { w00 = 0.f; w01 = 0.f; }
  if (iy1 < 0 || iy1 >= H) { w10 = 0.f; w11 = 0.f; }
  if (ix0 < 0 || ix0 >= W) { w00 = 0.f; w10 = 0.f; }
  if (ix1 < 0 || ix1 >= W) { w01 = 0.f; w11 = 0.f; }
  int cy0 = min(max(iy0, 0), H - 1), cy1 = min(max(iy1, 0), H - 1);
  int cx0 = min(max(ix0, 0), W - 1), cx1 = min(max(ix1, 0), W - 1);
  int c = c4 << 2;
  size_t rowb = (size_t)b * HW;
  float4 v00 = *(const float4*)(act + (rowb + cy0 * W + cx0) * C + c);
  float4 v01 = *(const float4*)(act + (rowb + cy0 * W + cx1) * C + c);
  float4 v10 = *(const float4*)(act + (rowb + cy1 * W + cx0) * C + c);
  float4 v11 = *(const float4*)(act + (rowb + cy1 * W + cx1) * C + c);
  if (bnmode) {
    float4 sc = *(const float4*)(stp + c);
    float4 sh = *(const float4*)(stp + 512 + c);
    v00.x = fmaxf(v00.x * sc.x + sh.x, 0.f); v00.y = fmaxf(v00.y * sc.y + sh.y, 0.f);
    v00.z = fmaxf(v00.z * sc.z + sh.z, 0.f); v00.w = fmaxf(v00.w * sc.w + sh.w, 0.f);
    v01.x = fmaxf(v01.x * sc.x + sh.x, 0.f); v01.y = fmaxf(v01.y * sc.y + sh.y, 0.f);
    v01.z = fmaxf(v01.z * sc.z + sh.z, 0.f); v01.w = fmaxf(v01.w * sc.w + sh.w, 0.f);
    v10.x = fmaxf(v10.x * sc.x + sh.x, 0.f); v10.y = fmaxf(v10.y * sc.y + sh.y, 0.f);
    v10.z = fmaxf(v10.z * sc.z + sh.z, 0.f); v10.w = fmaxf(v10.w * sc.w + sh.w, 0.f);
    v11.x = fmaxf(v11.x * sc.x + sh.x, 0.f); v11.y = fmaxf(v11.y * sc.y + sh.y, 0.f);
    v11.z = fmaxf(v11.z * sc.z + sh.z, 0.f); v11.w = fmaxf(v11.w * sc.w + sh.w, 0.f);
  }
  float4 r;
  r.x = w00 * v00.x + w01 * v01.x + w10 * v10.x + w11 * v11.x;
  r.y = w00 * v00.y + w01 * v01.y + w10 * v10.y + w11 * v11.y;
  r.z = w00 * v00.z + w01 * v01.z + w10 * v10.z + w11 * v11.z;
  r.w = w00 * v00.w + w01 * v01.w + w10 * v10.w + w11 * v11.w;
  *(float4*)(S + ((size_t)ml * 9 + k2) * C + c) = r;
}

// ------- scalar variant for C not divisible by 4 (layer 1, C=3) -------
__global__ __launch_bounds__(256) void deform_sample_scalar(
    const float* __restrict__ act, const float* __restrict__ off,
    float* __restrict__ S, int m0, int Mc, int B, int H, int W, int C) {
  int i = blockIdx.x * blockDim.x + threadIdx.x;
  int total = Mc * 9 * C;
  if (i >= total) return;
  int c = i % C;
  int t = i / C;
  int k2 = t % 9;
  int ml = t / 9;
  int m = m0 + ml;
  int HW = H * W;
  int b = m / HW; int p = m - b * HW; int y = p / W; int x = p - y * W;
  size_t ob = (size_t)b * 18 * HW + p;
  float dy = off[ob + (size_t)(2 * k2) * HW];
  float dx = off[ob + (size_t)(2 * k2 + 1) * HW];
  float py = (float)(y + k2 / 3 - 1) + dy;
  float px = (float)(x + k2 % 3 - 1) + dx;
  float y0f = floorf(py), x0f = floorf(px);
  float wy = py - y0f, wx = px - x0f;
  int iy0 = (int)y0f, ix0 = (int)x0f;
  int iy1 = iy0 + 1, ix1 = ix0 + 1;
  float w00 = (1.f - wy) * (1.f - wx), w01 = (1.f - wy) * wx;
  float w10 = wy * (1.f - wx), w11 = wy * wx;
  if (iy0 < 0 || iy0 >= H) { w00 = 0.f; w01 = 0.f; }
  if (iy1 < 0 || iy1 >= H) { w10 = 0.f; w11 = 0.f; }
  if (ix0 < 0 || ix0 >= W) { w00 = 0.f; w10 = 0.f; }
  if (ix1 < 0 || ix1 >= W) { w01 = 0.f; w11 = 0.f; }
  int cy0 = min(max(iy0, 0), H - 1), cy1 = min(max(iy1, 0), H - 1);
  int cx0 = min(max(ix0, 0), W - 1), cx1 = min(max(ix1, 0), W - 1);
  size_t rowb = (size_t)b * HW;
  float v00 = act[(rowb + cy0 * W + cx0) * C + c];
  float v01 = act[(rowb + cy0 * W + cx1) * C + c];
  float v10 = act[(rowb + cy1 * W + cx0) * C + c];
  float v11 = act[(rowb + cy1 * W + cx1) * C + c];
  S[((size_t)ml * 9 + k2) * C + c] = w00 * v00 + w01 * v01 + w10 * v10 + w11 * v11;
}

// ---------------- MFMA GEMM, split-K capable ----------------
#define LDA 40

union VecU {
  unsigned short u[8];
  short8 s;
};

__global__ __launch_bounds__(256) void mfma_gemm(
    const float* __restrict__ A, const float* __restrict__ Bw,
    const float* __restrict__ bias, float* __restrict__ Cf,
    int M, int N, int K, int relu, int kPerZ) {
  __shared__ __align__(16) unsigned short sAh[64 * LDA];
  __shared__ __align__(16) unsigned short sAl[64 * LDA];
  __shared__ __align__(16) unsigned short sBh[64 * LDA];
  __shared__ __align__(16) unsigned short sBl[64 * LDA];

  int tid = threadIdx.x;
  int wave = tid >> 6, lane = tid & 63;
  int quad = lane >> 4, l15 = lane & 15;
  int wr = wave >> 1, wc = wave & 1;
  int m0 = blockIdx.x * 64, n0 = blockIdx.y * 64;
  int kStart = blockIdx.z * kPerZ;
  int kEnd = min(K, kStart + kPerZ);

  f32x4 acc[2][2];
#pragma unroll
  for (int t = 0; t < 2; ++t)
#pragma unroll
    for (int u = 0; u < 2; ++u)
      acc[t][u] = (f32x4){0.f, 0.f, 0.f, 0.f};

  int r = tid >> 2;           // staging row 0..63
  int kk = (tid & 3) << 3;    // staging k offset 0,8,16,24
  bool vecOK = ((K & 7) == 0);

  for (int k0 = kStart; k0 < kEnd; k0 += 32) {
    __syncthreads();
    int gk = k0 + kk;
    {  // A tile: f32 -> (hi,lo) bf16 split
      int gm = m0 + r;
      unsigned short* dh = &sAh[r * LDA + kk];
      unsigned short* dl = &sAl[r * LDA + kk];
      float vv[8];
      if (gm < M && vecOK && gk + 8 <= K) {
        const float4* ap = (const float4*)(A + (size_t)gm * K + gk);
        float4 f0 = ap[0], f1 = ap[1];
        vv[0] = f0.x; vv[1] = f0.y; vv[2] = f0.z; vv[3] = f0.w;
        vv[4] = f1.x; vv[5] = f1.y; vv[6] = f1.z; vv[7] = f1.w;
      } else {
#pragma unroll
        for (int j = 0; j < 8; ++j)
          vv[j] = (gm < M && gk + j < K) ? A[(size_t)gm * K + gk + j] : 0.f;
      }
      VecU uh, ul;
#pragma unroll
      for (int j = 0; j < 8; ++j) {
        unsigned short hb = f2bfbits(vv[j]);
        uh.u[j] = hb;
        ul.u[j] = f2bfbits(vv[j] - bfbits2f(hb));
      }
      *(short8*)dh = uh.s;
      *(short8*)dl = ul.s;
    }
    {  // B tile: f32 -> (hi,lo) bf16 split
      int gn = n0 + r;
      unsigned short* dh = &sBh[r * LDA + kk];
      unsigned short* dl = &sBl[r * LDA + kk];
      float vv[8];
      if (gn < N && vecOK && gk + 8 <= K) {
        const float4* bp = (const float4*)(Bw + (size_t)gn * K + gk);
        float4 f0 = bp[0], f1 = bp[1];
        vv[0] = f0.x; vv[1] = f0.y; vv[2] = f0.z; vv[3] = f0.w;
        vv[4] = f1.x; vv[5] = f1.y; vv[6] = f1.z; vv[7] = f1.w;
      } else {
#pragma unroll
        for (int j = 0; j < 8; ++j)
          vv[j] = (gn < N && gk + j < K) ? Bw[(size_t)gn * K + gk + j] : 0.f;
      }
      VecU uh, ul;
#pragma unroll
      for (int j = 0; j < 8; ++j) {
        unsigned short hb = f2bfbits(vv[j]);
        uh.u[j] = hb;
        ul.u[j] = f2bfbits(vv[j] - bfbits2f(hb));
      }
      *(short8*)dh = uh.s;
      *(short8*)dl = ul.s;
    }
    __syncthreads();
    short8 ah0 = *(const short8*)&sAh[(wr * 32 + 0 + l15) * LDA + quad * 8];
    short8 ah1 = *(const short8*)&sAh[(wr * 32 + 16 + l15) * LDA + quad * 8];
    short8 al0 = *(const short8*)&sAl[(wr * 32 + 0 + l15) * LDA + quad * 8];
    short8 al1 = *(const short8*)&sAl[(wr * 32 + 16 + l15) * LDA + quad * 8];
    short8 bh0 = *(const short8*)&sBh[(wc * 32 + 0 + l15) * LDA + quad * 8];
    short8 bh1 = *(const short8*)&sBh[(wc * 32 + 16 + l15) * LDA + quad * 8];
    short8 bl0 = *(const short8*)&sBl[(wc * 32 + 0 + l15) * LDA + quad * 8];
    short8 bl1 = *(const short8*)&sBl[(wc * 32 + 16 + l15) * LDA + quad * 8];
    acc[0][0] = __builtin_amdgcn_mfma_f32_16x16x32_bf16(ah0, bh0, acc[0][0], 0, 0, 0);
    acc[0][1] = __builtin_amdgcn_mfma_f32_16x16x32_bf16(ah0, bh1, acc[0][1], 0, 0, 0);
    acc[1][0] = __builtin_amdgcn_mfma_f32_16x16x32_bf16(ah1, bh0, acc[1][0], 0, 0, 0);
    acc[1][1] = __builtin_amdgcn_mfma_f32_16x16x32_bf16(ah1, bh1, acc[1][1], 0, 0, 0);
    acc[0][0] = __builtin_amdgcn_mfma_f32_16x16x32_bf16(ah0, bl0, acc[0][0], 0, 0, 0);
    acc[0][1] = __builtin_amdgcn_mfma_f32_16x16x32_bf16(ah0, bl1, acc[0][1], 0, 0, 0);
    acc[1][0] = __builtin_amdgcn_mfma_f32_16x16x32_bf16(ah1, bl0, acc[1][0], 0, 0, 0);
    acc[1][1] = __builtin_amdgcn_mfma_f32_16x16x32_bf16(ah1, bl1, acc[1][1], 0, 0, 0);
    acc[0][0] = __builtin_amdgcn_mfma_f32_16x16x32_bf16(al0, bh0, acc[0][0], 0, 0, 0);
    acc[0][1] = __builtin_amdgcn_mfma_f32_16x16x32_bf16(al0, bh1, acc[0][1], 0, 0, 0);
    acc[1][0] = __builtin_amdgcn_mfma_f32_16x16x32_bf16(al1, bh0, acc[1][0], 0, 0, 0);
    acc[1][1] = __builtin_amdgcn_mfma_f32_16x16x32_bf16(al1, bh1, acc[1][1], 0, 0, 0);
  }

  bool atomicMode = (gridDim.z > 1);
#pragma unroll
  for (int t = 0; t < 2; ++t)
#pragma unroll
    for (int reg = 0; reg < 4; ++reg) {
      int m = m0 + wr * 32 + t * 16 + quad * 4 + reg;
      if (m >= M) continue;
#pragma unroll
      for (int u = 0; u < 2; ++u) {
        int n = n0 + wc * 32 + u * 16 + l15;
        if (n >= N) continue;
        float v = acc[t][u][reg];
        if (atomicMode) {
          atomicAdd(&Cf[(size_t)m * N + n], v);
        } else {
          if (bias) v += bias[n];
          if (relu && v < 0.f) v = 0.f;
          Cf[(size_t)m * N + n] = v;
        }
      }
    }
}

// ---------------- bias (+optional relu) pass for split-K outputs ----------------
__global__ void bias_act_kernel(float* __restrict__ x, const float* __restrict__ bias,
                                int total, int C, int relu) {
  int i = blockIdx.x * blockDim.x + threadIdx.x;
  if (i >= total) return;
  float v = x[i] + bias[i % C];
  if (relu && v < 0.f) v = 0.f;
  x[i] = v;
}

// ---------------- BN batch stats ----------------
__global__ __launch_bounds__(256) void bn_stats_kernel(const float* __restrict__ x,
                                                       float* __restrict__ st,
                                                       int M, int C, int rowsPerBlock) {
  __shared__ float sh[512];
  int t = threadIdx.x;
  int r0 = blockIdx.x * rowsPerBlock;
  int r1 = min(M, r0 + rowsPerBlock);
  if (C >= 256) {
    for (int c = t; c < C; c += 256) {
      float s = 0.f, ss = 0.f;
      for (int r = r0; r < r1; ++r) {
        float v = x[(size_t)r * C + c];
        s += v; ss += v * v;
      }
      atomicAdd(&st[c], s); atomicAdd(&st[512 + c], ss);
    }
  } else {
    int rpb = 256 / C;
    int c = t % C; int ro = t / C;
    float s = 0.f, ss = 0.f;
    for (int r = r0 + ro; r < r1; r += rpb) {
      float v = x[(size_t)r * C + c];
      s += v; ss += v * v;
    }
    sh[t] = s; sh[256 + t] = ss;
    __syncthreads();
    if (ro == 0) {
      for (int k = 1; k < rpb; ++k) { s += sh[k * C + c]; ss += sh[256 + k * C + c]; }
      atomicAdd(&st[c], s); atomicAdd(&st[512 + c], ss);
    }
  }
}

__global__ void bn_finalize_kernel(float* __restrict__ st, const float* __restrict__ g,
                                   const float* __restrict__ bb, int M, int C) {
  int c = threadIdx.x;
  if (c >= C) return;
  float mean = st[c] / (float)M;
  float var = st[512 + c] / (float)M - mean * mean;
  if (var < 0.f) var = 0.f;
  float inv = 1.0f / sqrtf(var + 1e-5f);
  float sc = g[c] * inv;
  st[1024 + c] = sc;
  st[1536 + c] = bb[c] - mean * sc;
}

// -------- permuted 2x2 max pool with fused BN+ReLU on inputs --------
__global__ void pool_kernel(const float* __restrict__ in, const float* __restrict__ stp,
                            float* __restrict__ out,
                            const int* __restrict__ perm, const int* __restrict__ nperm,
                            int B, int H, int C, int total) {
  int i = blockIdx.x * blockDim.x + threadIdx.x;
  if (i >= total) return;
  int oH = H / 2; int oHW = oH * oH; int HW = H * H;
  int c = i % C; int j = (i / C) % oHW; int b = i / (C * oHW);
  float sc = stp[c], sh = stp[512 + c];
  int q = min(max(nperm[j], 0), oHW - 1);
  int qy = q / oH, qx = q % oH;
  float m = 0.f;  // post-ReLU values are >= 0
#pragma unroll
  for (int dy = 0; dy < 2; ++dy)
#pragma unroll
    for (int dx = 0; dx < 2; ++dx) {
      int p = min(max(perm[(2 * qy + dy) * H + (2 * qx + dx)], 0), HW - 1);
      float v = in[((size_t)b * HW + p) * C + c];
      v = fmaxf(v * sc + sh, 0.f);
      m = fmaxf(m, v);
    }
  out[((size_t)b * oHW + j) * C + c] = m;
}

static inline void pick_split(int gx, int gy, int K, int& zs, int& kPerZ) {
  int gxy = gx * gy;
  zs = 1;
  if (gxy < 192) {
    zs = (256 + gxy - 1) / gxy;
    int maxz = K / 32; if (maxz < 1) maxz = 1;
    if (zs > maxz) zs = maxz;
  }
  kPerZ = (((K + zs - 1) / zs) + 31) & ~31;
}

extern "C" void kernel_launch(void* const* d_in, const int* in_sizes, int n_in,
                              void* d_out, int out_size, void* d_ws, size_t ws_size,
                              hipStream_t stream) {
  const int Ci[13]  = {3, 64, 64, 128, 128, 256, 256, 256, 512, 512, 512, 512, 512};
  const int CoA[13] = {64, 64, 128, 128, 256, 256, 256, 512, 512, 512, 512, 512, 512};
  const int Rr[13]  = {32, 32, 16, 16, 8, 8, 8, 4, 4, 4, 2, 2, 2};
  const int poolAfter[13] = {-1, 0, -1, 1, -1, -1, 2, -1, -1, 3, -1, -1, 4};
  const int B = 32;

  size_t cursor = 0;
  auto alloc = [&](size_t bytes) {
    void* p = (char*)d_ws + cursor;
    cursor += (bytes + 255) & ~(size_t)255;
    return p;
  };
  float* stats = (float*)alloc((size_t)13 * 2048 * 4);
  float* fcA   = (float*)alloc((size_t)32 * 4096 * 4);
  float* fcB   = (float*)alloc((size_t)32 * 4096 * 4);
  float* A0    = (float*)alloc((size_t)2097152 * 4);   // 32768*64 fp32
  float* A1    = (float*)alloc((size_t)2097152 * 4);
  float* WTf   = (float*)alloc((size_t)2359296 * 4);   // 512*4608 f32
  size_t remainBytes = (ws_size > cursor) ? (ws_size - cursor) : 0;
  size_t sFloats = remainBytes / 4;
  if (sFloats > (size_t)8388608) sFloats = 8388608;    // cap S at 32 MB
  if (sFloats < (size_t)294912)  sFloats = 294912;     // floor: 64 rows x K=4608
  float* S = (float*)alloc(sFloats * 4);
  (void)in_sizes; (void)n_in; (void)out_size;

  hipMemsetAsync(stats, 0, (size_t)13 * 2048 * 4, stream);

  {
    int total = B * 3 * 1024;
    nchw2nhwc_kernel<<<(total + 255) / 256, 256, 0, stream>>>(
        (const float*)d_in[0], A0, B, 3, 1024);
  }

  float* cur = A0;
  float* oth = A1;
  int needBN = 0;
  float* stp = nullptr;

  for (int l = 0; l < 13; ++l) {
    int C = Ci[l], N = CoA[l], H = Rr[l];
    int M = B * H * H, K = 9 * C;
    const float* offp = (const float*)d_in[1 + l * 5 + 0];
    const float* wp   = (const float*)d_in[1 + l * 5 + 1];
    const float* gp   = (const float*)d_in[1 + l * 5 + 3];
    const float* bbp  = (const float*)d_in[1 + l * 5 + 4];
    float* st = stats + (size_t)l * 2048;

    wt_kernel<<<(N * K + 255) / 256, 256, 0, stream>>>(wp, WTf, N, C);

    int MC = (int)((sFloats / (size_t)K) & ~(size_t)63);
    if (MC < 64) MC = 64;
    if (MC > M) MC = M;
    for (int r0 = 0; r0 < M; r0 += MC) {
      int Mc = min(MC, M - r0);
      if ((C & 3) == 0) {
        int work = Mc * 9 * (C >> 2);
        deform_sample_v2<<<(work + 255) / 256, 256, 0, stream>>>(
            cur, stp, needBN, offp, S, r0, Mc, B, H, H, C);
      } else {
        int work = Mc * 9 * C;
        deform_sample_scalar<<<(work + 255) / 256, 256, 0, stream>>>(
            cur, offp, S, r0, Mc, B, H, H, C);
      }
      int gx = (Mc + 63) / 64, gy = (N + 63) / 64;
      int zs, kPerZ;
      pick_split(gx, gy, K, zs, kPerZ);
      if (zs > 1)
        hipMemsetAsync(oth + (size_t)r0 * N, 0, (size_t)Mc * N * 4, stream);
      dim3 gg(gx, gy, zs);
      mfma_gemm<<<gg, 256, 0, stream>>>(S, WTf, nullptr, oth + (size_t)r0 * N,
                                        Mc, N, K, 0, kPerZ);
    }

    int rowsPer = 64;
    bn_stats_kernel<<<(M + rowsPer - 1) / rowsPer, 256, 0, stream>>>(oth, st, M, N, rowsPer);
    bn_finalize_kernel<<<1, 512, 0, stream>>>(st, gp, bbp, M, N);

    if (poolAfter[l] >= 0) {
      int pi = poolAfter[l];
      const int* perm  = (const int*)d_in[66 + pi * 2];
      const int* nperm = (const int*)d_in[66 + pi * 2 + 1];
      int oH = H / 2;
      int total = B * oH * oH * N;
      pool_kernel<<<(total + 255) / 256, 256, 0, stream>>>(oth, st + 1024, cur,
                                                           perm, nperm, B, H, N, total);
      needBN = 0; stp = nullptr;
    } else {
      float* t = cur; cur = oth; oth = t;
      needBN = 1; stp = st + 1024;
    }
  }

  // FC head: cur = [32, 512] fp32 activated
  const float* fw1 = (const float*)d_in[76]; const float* fb1 = (const float*)d_in[77];
  const float* fw2 = (const float*)d_in[78]; const float* fb2 = (const float*)d_in[79];
  const float* fw3 = (const float*)d_in[80]; const float* fb3 = (const float*)d_in[81];
  {
    int zs, kPerZ;
    // FC1: 32x4096x512
    hipMemsetAsync(fcA, 0, (size_t)32 * 4096 * 4, stream);
    pick_split(1, 64, 512, zs, kPerZ);
    mfma_gemm<<<dim3(1, 64, zs), 256, 0, stream>>>(cur, fw1, nullptr, fcA,
                                                   32, 4096, 512, 0, kPerZ);
    bias_act_kernel<<<(32 * 4096 + 255) / 256, 256, 0, stream>>>(fcA, fb1, 32 * 4096, 4096, 1);
    // FC2: 32x4096x4096
    hipMemsetAsync(fcB, 0, (size_t)32 * 4096 * 4, stream);
    pick_split(1, 64, 4096, zs, kPerZ);
    mfma_gemm<<<dim3(1, 64, zs), 256, 0, stream>>>(fcA, fw2, nullptr, fcB,
                                                   32, 4096, 4096, 0, kPerZ);
    bias_act_kernel<<<(32 * 4096 + 255) / 256, 256, 0, stream>>>(fcB, fb2, 32 * 4096, 4096, 1);
    // FC3: 32x100x4096
    hipMemsetAsync(d_out, 0, (size_t)3200 * 4, stream);
    pick_split(1, 2, 4096, zs, kPerZ);
    mfma_gemm<<<dim3(1, 2, zs), 256, 0, stream>>>(fcB, fw3, nullptr, (float*)d_out,
                                                  32, 100, 4096, 0, kPerZ);
    bias_act_kernel<<<(3200 + 255) / 256, 256, 0, stream>>>((float*)d_out, fb3, 3200, 100, 0);
  }
}